// Round 12
// baseline (493.008 us; speedup 1.0000x reference)
//
#include <hip/hip_runtime.h>
#include <hip/hip_bf16.h>

constexpr int D_ = 64;
constexpr int NN = 100000;
constexpr int NE = 1600000;
constexpr int RB = 8;        // rows per wave-batch in gemm2

// ---- sort-CSR parameters
constexpr int BUCK_SH = 7;                         // 128 nodes per bucket
constexpr int NBUCK = (NN + 127) >> BUCK_SH;       // 782
constexpr int NB1 = 256;                           // S1 grid
constexpr int NQ4 = NE / 4;                        // 400000 quads
constexpr int QPB = (NQ4 + NB1 - 1) / NB1;         // 1563 quads/block
constexpr int SCN = NBUCK * NB1;                   // 200192 count entries
constexpr int SCB = (SCN + 1023) / 1024;           // 196 scan blocks

__device__ __forceinline__ float bflo(unsigned v) { return __uint_as_float(v << 16); }
__device__ __forceinline__ float bfhi(unsigned v) { return __uint_as_float(v & 0xffff0000u); }

// ---- S1A: per-block LDS histogram of endpoint buckets (no global atomics)
__global__ __launch_bounds__(256) void k_s1count(const int* __restrict__ edges,
                                                 int* __restrict__ cnts) {
  __shared__ int hist[NBUCK];
  for (int i = threadIdx.x; i < NBUCK; i += 256) hist[i] = 0;
  __syncthreads();
  const int q0 = blockIdx.x * QPB;
  const int q1 = min(q0 + QPB, NQ4);
  for (int q = q0 + (int)threadIdx.x; q < q1; q += 256) {
    const int4* ep = reinterpret_cast<const int4*>(edges + 8 * q);
    int4 a = ep[0], b = ep[1];
    atomicAdd(&hist[a.x >> BUCK_SH], 1);
    atomicAdd(&hist[a.y >> BUCK_SH], 1);
    atomicAdd(&hist[a.z >> BUCK_SH], 1);
    atomicAdd(&hist[a.w >> BUCK_SH], 1);
    atomicAdd(&hist[b.x >> BUCK_SH], 1);
    atomicAdd(&hist[b.y >> BUCK_SH], 1);
    atomicAdd(&hist[b.z >> BUCK_SH], 1);
    atomicAdd(&hist[b.w >> BUCK_SH], 1);
  }
  __syncthreads();
  for (int i = threadIdx.x; i < NBUCK; i += 256)
    cnts[i * NB1 + blockIdx.x] = hist[i];  // bucket-major for linear scan
}

// ---- hierarchical scan A (1024-wide blocks)
__global__ __launch_bounds__(1024) void k_scanA(const int* __restrict__ cnt,
                                                int* __restrict__ oscan,
                                                int* __restrict__ bsum, int n) {
  __shared__ int sd[1024];
  const int tid = threadIdx.x;
  const int i = blockIdx.x * 1024 + tid;
  int v = (i < n) ? cnt[i] : 0;
  sd[tid] = v;
  __syncthreads();
  for (int off = 1; off < 1024; off <<= 1) {
    int t = (tid >= off) ? sd[tid - off] : 0;
    __syncthreads();
    sd[tid] += t;
    __syncthreads();
  }
  if (i < n) oscan[i] = sd[tid] - v;
  if (tid == 1023) bsum[blockIdx.x] = sd[1023];
}

// ---- scan B: single 256-thread block scans block totals (exclusive, in place)
__global__ __launch_bounds__(256) void k_scanB(int* __restrict__ bsum, int nb) {
  __shared__ int sd[256];
  const int tid = threadIdx.x;
  int v = (tid < nb) ? bsum[tid] : 0;
  sd[tid] = v;
  __syncthreads();
  for (int off = 1; off < 256; off <<= 1) {
    int t = (tid >= off) ? sd[tid - off] : 0;
    __syncthreads();
    sd[tid] += t;
    __syncthreads();
  }
  if (tid < nb) bsum[tid] = sd[tid] - v;
}

// ---- scan C: add block base
__global__ __launch_bounds__(256) void k_scanC(int* __restrict__ oscan,
                                               const int* __restrict__ bsum, int n) {
  int i = blockIdx.x * 256 + threadIdx.x;
  if (i < n) oscan[i] += bsum[i >> 10];
}

// ---- S1B: scatter items into bucket-sorted array via LDS cursors.
__global__ __launch_bounds__(256) void k_s1scatter(const int* __restrict__ edges,
                                                   const int* __restrict__ sscan,
                                                   unsigned* __restrict__ items) {
  __shared__ int cur[NBUCK];
  for (int i = threadIdx.x; i < NBUCK; i += 256)
    cur[i] = sscan[i * NB1 + blockIdx.x];
  __syncthreads();
  const int q0 = blockIdx.x * QPB;
  const int q1 = min(q0 + QPB, NQ4);
  for (int q = q0 + (int)threadIdx.x; q < q1; q += 256) {
    const int4* ep = reinterpret_cast<const int4*>(edges + 8 * q);
    int4 a = ep[0], b = ep[1];
    int p;
    p = atomicAdd(&cur[a.y >> BUCK_SH], 1); items[p] = ((unsigned)(a.y & 127) << 17) | (unsigned)a.x;
    p = atomicAdd(&cur[a.x >> BUCK_SH], 1); items[p] = ((unsigned)(a.x & 127) << 17) | (unsigned)a.y;
    p = atomicAdd(&cur[a.w >> BUCK_SH], 1); items[p] = ((unsigned)(a.w & 127) << 17) | (unsigned)a.z;
    p = atomicAdd(&cur[a.z >> BUCK_SH], 1); items[p] = ((unsigned)(a.z & 127) << 17) | (unsigned)a.w;
    p = atomicAdd(&cur[b.y >> BUCK_SH], 1); items[p] = ((unsigned)(b.y & 127) << 17) | (unsigned)b.x;
    p = atomicAdd(&cur[b.x >> BUCK_SH], 1); items[p] = ((unsigned)(b.x & 127) << 17) | (unsigned)b.y;
    p = atomicAdd(&cur[b.w >> BUCK_SH], 1); items[p] = ((unsigned)(b.w & 127) << 17) | (unsigned)b.z;
    p = atomicAdd(&cur[b.z >> BUCK_SH], 1); items[p] = ((unsigned)(b.z & 127) << 17) | (unsigned)b.w;
  }
}

// ---- S2: one block per bucket -> local histogram+scan -> offs + nbr placement
__global__ __launch_bounds__(256) void k_s2build(const unsigned* __restrict__ items,
                                                 const int* __restrict__ sscan,
                                                 int* __restrict__ offs,
                                                 int* __restrict__ nbr) {
  const int b = blockIdx.x;
  const int lo = b << BUCK_SH;
  __shared__ int hist[128], scn[128];
  __shared__ int sbase, send;
  if (threadIdx.x == 0) {
    sbase = sscan[b * NB1];
    send = (b + 1 < NBUCK) ? sscan[(b + 1) * NB1] : 2 * NE;
  }
  if (threadIdx.x < 128) hist[threadIdx.x] = 0;
  __syncthreads();
  const int i0 = sbase, i1 = send;
  for (int i = i0 + (int)threadIdx.x; i < i1; i += 256)
    atomicAdd(&hist[items[i] >> 17], 1);
  __syncthreads();
  if (threadIdx.x < 128) scn[threadIdx.x] = hist[threadIdx.x];
  __syncthreads();
  for (int off = 1; off < 128; off <<= 1) {
    int t = (threadIdx.x < 128 && (int)threadIdx.x >= off) ? scn[threadIdx.x - off] : 0;
    __syncthreads();
    if (threadIdx.x < 128) scn[threadIdx.x] += t;
    __syncthreads();
  }
  if (threadIdx.x < 128) {
    int node = lo + threadIdx.x;
    int ex = sbase + scn[threadIdx.x] - hist[threadIdx.x];
    if (node < NN) offs[node] = ex;
    hist[threadIdx.x] = ex;  // placement cursor
  }
  __syncthreads();
  for (int i = i0 + (int)threadIdx.x; i < i1; i += 256) {
    unsigned it = items[i];
    int pos = atomicAdd(&hist[it >> 17], 1);
    nbr[pos] = (int)(it & 0x1FFFFu);
  }
  if (b == 0 && threadIdx.x == 0) offs[NN] = 2 * NE;
}

// W staged transposed+padded: wT[j*68+k] = W[k*64+j]
__device__ __forceinline__ void stage_w(const float* __restrict__ W, float* wT) {
  for (int i = threadIdx.x; i < 4096; i += 256) {
    int k = i >> 6, j = i & 63;
    wT[j * 68 + k] = W[i];
  }
}

// ---- gemm2: base = h@W0+b0 (f32), msg = bf16(h@W1+b1).
// k4 loop rolled (#pragma unroll 1): prevents LICM VGPR blowup (R8/R9).
__global__ __launch_bounds__(256) void k_gemm2(
    const float* __restrict__ h, const float* __restrict__ W0,
    const float* __restrict__ b0, const float* __restrict__ W1,
    const float* __restrict__ b1, float* __restrict__ base,
    __hip_bfloat16* __restrict__ msg, int nrows) {
  __shared__ float w0T[64 * 68];
  __shared__ float w1T[64 * 68];
  __shared__ float rbuf[4][RB * 64];
  stage_w(W0, w0T);
  stage_w(W1, w1T);
  __syncthreads();
  const int lane = threadIdx.x & 63;
  const int wv = threadIdx.x >> 6;
  const int wid = (blockIdx.x * 256 + threadIdx.x) >> 6;
  const int nw = (gridDim.x * 256) >> 6;
  const float bv0 = b0[lane], bv1 = b1[lane];
  const float4* wl0 = reinterpret_cast<const float4*>(&w0T[lane * 68]);
  const float4* wl1 = reinterpret_cast<const float4*>(&w1T[lane * 68]);
  float* myrows = rbuf[wv];

  const int chunk = (nrows + nw - 1) / nw;
  const int r0 = wid * chunk;
  const int r1 = min(r0 + chunk, nrows);
  if (r0 >= nrows) return;

  float st[RB];
#pragma unroll
  for (int rr = 0; rr < RB; ++rr) {
    int r = min(r0 + rr, nrows - 1);
    st[rr] = h[(size_t)r * 64 + lane];
  }
  for (int rb = r0; rb < r1; rb += RB) {
#pragma unroll
    for (int rr = 0; rr < RB; ++rr) myrows[rr * 64 + lane] = st[rr];
    const int nb = rb + RB;
    if (nb < r1) {
#pragma unroll
      for (int rr = 0; rr < RB; ++rr) {
        int r = min(nb + rr, nrows - 1);
        st[rr] = h[(size_t)r * 64 + lane];
      }
    }
    float a0[RB], a1[RB];
#pragma unroll
    for (int rr = 0; rr < RB; ++rr) { a0[rr] = bv0; a1[rr] = bv1; }
#pragma unroll 1
    for (int k4 = 0; k4 < 16; ++k4) {
      const float4 v0 = wl0[k4];
      const float4 v1 = wl1[k4];
#pragma unroll
      for (int rr = 0; rr < RB; ++rr) {
        float4 hv = *reinterpret_cast<const float4*>(&myrows[rr * 64 + k4 * 4]);
        a0[rr] = fmaf(hv.x, v0.x, a0[rr]); a1[rr] = fmaf(hv.x, v1.x, a1[rr]);
        a0[rr] = fmaf(hv.y, v0.y, a0[rr]); a1[rr] = fmaf(hv.y, v1.y, a1[rr]);
        a0[rr] = fmaf(hv.z, v0.z, a0[rr]); a1[rr] = fmaf(hv.z, v1.z, a1[rr]);
        a0[rr] = fmaf(hv.w, v0.w, a0[rr]); a1[rr] = fmaf(hv.w, v1.w, a1[rr]);
      }
    }
#pragma unroll
    for (int rr = 0; rr < RB; ++rr) {
      int r = rb + rr;
      if (r < r1) {
        base[(size_t)r * 64 + lane] = a0[rr];
        msg[(size_t)r * 64 + lane] = __float2bfloat16(a1[rr]);
      }
    }
  }
}

// ---- gather: uint4 loads, 8 neighbor rows per instruction.
// Lane = grp*8 + sub: grp picks neighbor slot in chunk, sub picks 16B row slice.
template <bool LN>
__global__ __launch_bounds__(256) void k_agg(
    const float* __restrict__ base, const __hip_bfloat16* __restrict__ msg,
    const int* __restrict__ offs, const int* __restrict__ nbr,
    const float* __restrict__ gamma, const float* __restrict__ beta,
    float* __restrict__ out, int nrows) {
  const int lane = threadIdx.x & 63;
  const int wv = threadIdx.x >> 6;
  const int grp = lane >> 3;   // neighbor sub-slot (0..7)
  const int sub = lane & 7;    // 16B slice = columns [sub*8, sub*8+8)
  const int wid = (blockIdx.x * 256 + threadIdx.x) >> 6;
  const int nw = (gridDim.x * 256) >> 6;
  __shared__ float red[4][64];
  float gm = 1.0f, bt = 0.0f;
  if (LN) { gm = gamma[lane]; bt = beta[lane]; }
  const uint4* mp = reinterpret_cast<const uint4*>(msg);  // row = 8 uint4
  const uint4 z4 = {0u, 0u, 0u, 0u};
  for (int r = wid; r < nrows; r += nw) {
    const int n0 = offs[r], n1 = offs[r + 1];
    const float bval = base[(size_t)r * 64 + lane];
    float acc[8];
#pragma unroll
    for (int k = 0; k < 8; ++k) acc[k] = 0.0f;
    for (int jb = n0; jb < n1; jb += 64) {
      int myidx = (jb + lane < n1) ? nbr[jb + lane] : 0;  // coalesced 64 idx
      uint4 v[8];
#pragma unroll
      for (int c = 0; c < 8; ++c) {  // load phase: 8 gathers in flight
        int rowid = __shfl(myidx, c * 8 + grp, 64);
        v[c] = (jb + c * 8 + grp < n1) ? mp[(rowid << 3) | sub] : z4;
      }
#pragma unroll
      for (int c = 0; c < 8; ++c) {  // accumulate phase (vmcnt descends)
        acc[0] += bflo(v[c].x); acc[1] += bfhi(v[c].x);
        acc[2] += bflo(v[c].y); acc[3] += bfhi(v[c].y);
        acc[4] += bflo(v[c].z); acc[5] += bfhi(v[c].z);
        acc[6] += bflo(v[c].w); acc[7] += bfhi(v[c].w);
      }
    }
    // reduce over grp (xor 8/16/32 preserves sub)
#pragma unroll
    for (int off = 8; off < 64; off <<= 1)
#pragma unroll
      for (int k = 0; k < 8; ++k) acc[k] += __shfl_xor(acc[k], off, 64);
    // lanes 0..7 (sub==lane) hold columns [lane*8, lane*8+8): bounce via LDS
    if (lane < 8) {
#pragma unroll
      for (int k = 0; k < 8; ++k) red[wv][lane * 8 + k] = acc[k];
    }
    float ag = red[wv][lane];  // same-wave LDS RAW: in-order DS pipe
    const float rdeg = 1.0f / fmaxf((float)(n1 - n0), 1.0f);
    float val = fmaf(ag, rdeg, bval);
    if (LN) {
      float s = val;
#pragma unroll
      for (int off = 32; off > 0; off >>= 1) s += __shfl_xor(s, off, 64);
      const float mu = s * (1.0f / 64.0f);
      const float dv = val - mu;
      float v2 = dv * dv;
#pragma unroll
      for (int off = 32; off > 0; off >>= 1) v2 += __shfl_xor(v2, off, 64);
      const float var = v2 * (1.0f / 64.0f);
      val = fmaxf(fmaf(dv * rsqrtf(var + 1e-5f), gm, bt), 0.0f);
    }
    out[(size_t)r * 64 + lane] = val;
  }
}

extern "C" void kernel_launch(void* const* d_in, const int* in_sizes, int n_in,
                              void* d_out, int out_size, void* d_ws, size_t ws_size,
                              hipStream_t stream) {
  const float* vert = (const float*)d_in[0];
  const int* edges = (const int*)d_in[1];
  const float* W0 = (const float*)d_in[2];
  const float* b0 = (const float*)d_in[3];
  const float* W1 = (const float*)d_in[4];
  const float* b1 = (const float*)d_in[5];
  const float* lng = (const float*)d_in[6];
  const float* lnb = (const float*)d_in[7];
  float* base = (float*)d_out;  // base lives in d_out every layer

  const size_t HB = (size_t)NN * D_ * sizeof(float);  // 25.6 MB
  float* hbuf = (float*)d_ws;                                  // persistent h
  int* nbr = (int*)((char*)d_ws + HB);                         // 12.8 MB persistent
  char* msgreg = (char*)d_ws + HB + (size_t)2 * NE * 4;        // 12.8 MB region
  __hip_bfloat16* msg = (__hip_bfloat16*)msgreg;
  unsigned* items = (unsigned*)msgreg;  // CSR build temp (dead before msg)
  int* offs = (int*)((char*)d_ws + HB + (size_t)2 * NE * 4 + HB / 2);  // persistent
  // CSR scan temporaries live in d_out (dead before gemm2-L0 writes base)
  int* cnts = (int*)d_out;        // SCN ints
  int* sscan = cnts + SCN;        // SCN ints
  int* bsum = sscan + SCN;        // SCB ints

  // ---- CSR build: bucket sort, zero global atomics
  k_s1count<<<NB1, 256, 0, stream>>>(edges, cnts);
  k_scanA<<<SCB, 1024, 0, stream>>>(cnts, sscan, bsum, SCN);
  k_scanB<<<1, 256, 0, stream>>>(bsum, SCB);
  k_scanC<<<(SCN + 255) / 256, 256, 0, stream>>>(sscan, bsum, SCN);
  k_s1scatter<<<NB1, 256, 0, stream>>>(edges, sscan, items);
  k_s2build<<<NBUCK, 256, 0, stream>>>(items, sscan, offs, nbr);

  const int GB = 2048;   // agg grid (8192 waves = device wave capacity)
  const int GG = 1024;   // gemm2 grid

  for (int l = 0; l < 3; ++l) {
    const float* hcur = (l == 0) ? vert : hbuf;
    k_gemm2<<<GG, 256, 0, stream>>>(hcur, W0 + l * 4096, b0 + l * 64,
                                    W1 + l * 4096, b1 + l * 64, base, msg, NN);
    if (l < 2) {
      k_agg<true><<<GB, 256, 0, stream>>>(base, msg, offs, nbr,
                                          lng + l * 64, lnb + l * 64, hbuf, NN);
    } else {
      k_agg<false><<<GB, 256, 0, stream>>>(base, msg, offs, nbr,
                                           nullptr, nullptr, base, NN);
    }
  }
}

// Round 13
// 420.435 us; speedup vs baseline: 1.1726x; 1.1726x over previous
//
#include <hip/hip_runtime.h>
#include <hip/hip_bf16.h>

constexpr int D_ = 64;
constexpr int NN = 100000;
constexpr int NE = 1600000;
constexpr int RB = 8;        // rows per wave-batch in gemm2

// ---- sort-CSR parameters
constexpr int BUCK_SH = 7;                         // 128 nodes per bucket
constexpr int NBUCK = (NN + 127) >> BUCK_SH;       // 782
constexpr int NB1 = 256;                           // S1 grid
constexpr int NQ4 = NE / 4;                        // 400000 quads
constexpr int QPB = (NQ4 + NB1 - 1) / NB1;         // 1563 quads/block
constexpr int SCN = NBUCK * NB1;                   // 200192 count entries
constexpr int SCB = (SCN + 1023) / 1024;           // 196 scan blocks

__device__ __forceinline__ float bflo(unsigned v) { return __uint_as_float(v << 16); }
__device__ __forceinline__ float bfhi(unsigned v) { return __uint_as_float(v & 0xffff0000u); }

// ---- S1A: per-block LDS histogram of endpoint buckets (no global atomics)
__global__ __launch_bounds__(256) void k_s1count(const int* __restrict__ edges,
                                                 int* __restrict__ cnts) {
  __shared__ int hist[NBUCK];
  for (int i = threadIdx.x; i < NBUCK; i += 256) hist[i] = 0;
  __syncthreads();
  const int q0 = blockIdx.x * QPB;
  const int q1 = min(q0 + QPB, NQ4);
  for (int q = q0 + (int)threadIdx.x; q < q1; q += 256) {
    const int4* ep = reinterpret_cast<const int4*>(edges + 8 * q);
    int4 a = ep[0], b = ep[1];
    atomicAdd(&hist[a.x >> BUCK_SH], 1);
    atomicAdd(&hist[a.y >> BUCK_SH], 1);
    atomicAdd(&hist[a.z >> BUCK_SH], 1);
    atomicAdd(&hist[a.w >> BUCK_SH], 1);
    atomicAdd(&hist[b.x >> BUCK_SH], 1);
    atomicAdd(&hist[b.y >> BUCK_SH], 1);
    atomicAdd(&hist[b.z >> BUCK_SH], 1);
    atomicAdd(&hist[b.w >> BUCK_SH], 1);
  }
  __syncthreads();
  for (int i = threadIdx.x; i < NBUCK; i += 256)
    cnts[i * NB1 + blockIdx.x] = hist[i];  // bucket-major for linear scan
}

// ---- hierarchical scan A (1024-wide blocks)
__global__ __launch_bounds__(1024) void k_scanA(const int* __restrict__ cnt,
                                                int* __restrict__ oscan,
                                                int* __restrict__ bsum, int n) {
  __shared__ int sd[1024];
  const int tid = threadIdx.x;
  const int i = blockIdx.x * 1024 + tid;
  int v = (i < n) ? cnt[i] : 0;
  sd[tid] = v;
  __syncthreads();
  for (int off = 1; off < 1024; off <<= 1) {
    int t = (tid >= off) ? sd[tid - off] : 0;
    __syncthreads();
    sd[tid] += t;
    __syncthreads();
  }
  if (i < n) oscan[i] = sd[tid] - v;
  if (tid == 1023) bsum[blockIdx.x] = sd[1023];
}

// ---- scan B: single 256-thread block scans block totals (exclusive, in place)
__global__ __launch_bounds__(256) void k_scanB(int* __restrict__ bsum, int nb) {
  __shared__ int sd[256];
  const int tid = threadIdx.x;
  int v = (tid < nb) ? bsum[tid] : 0;
  sd[tid] = v;
  __syncthreads();
  for (int off = 1; off < 256; off <<= 1) {
    int t = (tid >= off) ? sd[tid - off] : 0;
    __syncthreads();
    sd[tid] += t;
    __syncthreads();
  }
  if (tid < nb) bsum[tid] = sd[tid] - v;
}

// ---- scan C: add block base
__global__ __launch_bounds__(256) void k_scanC(int* __restrict__ oscan,
                                               const int* __restrict__ bsum, int n) {
  int i = blockIdx.x * 256 + threadIdx.x;
  if (i < n) oscan[i] += bsum[i >> 10];
}

// ---- S1B: scatter items into bucket-sorted array via LDS cursors.
__global__ __launch_bounds__(256) void k_s1scatter(const int* __restrict__ edges,
                                                   const int* __restrict__ sscan,
                                                   unsigned* __restrict__ items) {
  __shared__ int cur[NBUCK];
  for (int i = threadIdx.x; i < NBUCK; i += 256)
    cur[i] = sscan[i * NB1 + blockIdx.x];
  __syncthreads();
  const int q0 = blockIdx.x * QPB;
  const int q1 = min(q0 + QPB, NQ4);
  for (int q = q0 + (int)threadIdx.x; q < q1; q += 256) {
    const int4* ep = reinterpret_cast<const int4*>(edges + 8 * q);
    int4 a = ep[0], b = ep[1];
    int p;
    p = atomicAdd(&cur[a.y >> BUCK_SH], 1); items[p] = ((unsigned)(a.y & 127) << 17) | (unsigned)a.x;
    p = atomicAdd(&cur[a.x >> BUCK_SH], 1); items[p] = ((unsigned)(a.x & 127) << 17) | (unsigned)a.y;
    p = atomicAdd(&cur[a.w >> BUCK_SH], 1); items[p] = ((unsigned)(a.w & 127) << 17) | (unsigned)a.z;
    p = atomicAdd(&cur[a.z >> BUCK_SH], 1); items[p] = ((unsigned)(a.z & 127) << 17) | (unsigned)a.w;
    p = atomicAdd(&cur[b.y >> BUCK_SH], 1); items[p] = ((unsigned)(b.y & 127) << 17) | (unsigned)b.x;
    p = atomicAdd(&cur[b.x >> BUCK_SH], 1); items[p] = ((unsigned)(b.x & 127) << 17) | (unsigned)b.y;
    p = atomicAdd(&cur[b.w >> BUCK_SH], 1); items[p] = ((unsigned)(b.w & 127) << 17) | (unsigned)b.z;
    p = atomicAdd(&cur[b.z >> BUCK_SH], 1); items[p] = ((unsigned)(b.z & 127) << 17) | (unsigned)b.w;
  }
}

// ---- S2: one block per bucket -> local histogram+scan -> offs + nbr placement
__global__ __launch_bounds__(256) void k_s2build(const unsigned* __restrict__ items,
                                                 const int* __restrict__ sscan,
                                                 int* __restrict__ offs,
                                                 int* __restrict__ nbr) {
  const int b = blockIdx.x;
  const int lo = b << BUCK_SH;
  __shared__ int hist[128], scn[128];
  __shared__ int sbase, send;
  if (threadIdx.x == 0) {
    sbase = sscan[b * NB1];
    send = (b + 1 < NBUCK) ? sscan[(b + 1) * NB1] : 2 * NE;
  }
  if (threadIdx.x < 128) hist[threadIdx.x] = 0;
  __syncthreads();
  const int i0 = sbase, i1 = send;
  for (int i = i0 + (int)threadIdx.x; i < i1; i += 256)
    atomicAdd(&hist[items[i] >> 17], 1);
  __syncthreads();
  if (threadIdx.x < 128) scn[threadIdx.x] = hist[threadIdx.x];
  __syncthreads();
  for (int off = 1; off < 128; off <<= 1) {
    int t = (threadIdx.x < 128 && (int)threadIdx.x >= off) ? scn[threadIdx.x - off] : 0;
    __syncthreads();
    if (threadIdx.x < 128) scn[threadIdx.x] += t;
    __syncthreads();
  }
  if (threadIdx.x < 128) {
    int node = lo + threadIdx.x;
    int ex = sbase + scn[threadIdx.x] - hist[threadIdx.x];
    if (node < NN) offs[node] = ex;
    hist[threadIdx.x] = ex;  // placement cursor
  }
  __syncthreads();
  for (int i = i0 + (int)threadIdx.x; i < i1; i += 256) {
    unsigned it = items[i];
    int pos = atomicAdd(&hist[it >> 17], 1);
    nbr[pos] = (int)(it & 0x1FFFFu);
  }
  if (b == 0 && threadIdx.x == 0) offs[NN] = 2 * NE;
}

// W staged transposed+padded: wT[j*68+k] = W[k*64+j]
__device__ __forceinline__ void stage_w(const float* __restrict__ W, float* wT) {
  for (int i = threadIdx.x; i < 4096; i += 256) {
    int k = i >> 6, j = i & 63;
    wT[j * 68 + k] = W[i];
  }
}

// ---- gemm2: base = h@W0+b0 (f32), msg = bf16(h@W1+b1).
// k4 loop rolled (#pragma unroll 1): prevents LICM VGPR blowup (R8/R9).
__global__ __launch_bounds__(256) void k_gemm2(
    const float* __restrict__ h, const float* __restrict__ W0,
    const float* __restrict__ b0, const float* __restrict__ W1,
    const float* __restrict__ b1, float* __restrict__ base,
    __hip_bfloat16* __restrict__ msg, int nrows) {
  __shared__ float w0T[64 * 68];
  __shared__ float w1T[64 * 68];
  __shared__ float rbuf[4][RB * 64];
  stage_w(W0, w0T);
  stage_w(W1, w1T);
  __syncthreads();
  const int lane = threadIdx.x & 63;
  const int wv = threadIdx.x >> 6;
  const int wid = (blockIdx.x * 256 + threadIdx.x) >> 6;
  const int nw = (gridDim.x * 256) >> 6;
  const float bv0 = b0[lane], bv1 = b1[lane];
  const float4* wl0 = reinterpret_cast<const float4*>(&w0T[lane * 68]);
  const float4* wl1 = reinterpret_cast<const float4*>(&w1T[lane * 68]);
  float* myrows = rbuf[wv];

  const int chunk = (nrows + nw - 1) / nw;
  const int r0 = wid * chunk;
  const int r1 = min(r0 + chunk, nrows);
  if (r0 >= nrows) return;

  float st[RB];
#pragma unroll
  for (int rr = 0; rr < RB; ++rr) {
    int r = min(r0 + rr, nrows - 1);
    st[rr] = h[(size_t)r * 64 + lane];
  }
  for (int rb = r0; rb < r1; rb += RB) {
#pragma unroll
    for (int rr = 0; rr < RB; ++rr) myrows[rr * 64 + lane] = st[rr];
    const int nb = rb + RB;
    if (nb < r1) {
#pragma unroll
      for (int rr = 0; rr < RB; ++rr) {
        int r = min(nb + rr, nrows - 1);
        st[rr] = h[(size_t)r * 64 + lane];
      }
    }
    float a0[RB], a1[RB];
#pragma unroll
    for (int rr = 0; rr < RB; ++rr) { a0[rr] = bv0; a1[rr] = bv1; }
#pragma unroll 1
    for (int k4 = 0; k4 < 16; ++k4) {
      const float4 v0 = wl0[k4];
      const float4 v1 = wl1[k4];
#pragma unroll
      for (int rr = 0; rr < RB; ++rr) {
        float4 hv = *reinterpret_cast<const float4*>(&myrows[rr * 64 + k4 * 4]);
        a0[rr] = fmaf(hv.x, v0.x, a0[rr]); a1[rr] = fmaf(hv.x, v1.x, a1[rr]);
        a0[rr] = fmaf(hv.y, v0.y, a0[rr]); a1[rr] = fmaf(hv.y, v1.y, a1[rr]);
        a0[rr] = fmaf(hv.z, v0.z, a0[rr]); a1[rr] = fmaf(hv.z, v1.z, a1[rr]);
        a0[rr] = fmaf(hv.w, v0.w, a0[rr]); a1[rr] = fmaf(hv.w, v1.w, a1[rr]);
      }
    }
#pragma unroll
    for (int rr = 0; rr < RB; ++rr) {
      int r = rb + rr;
      if (r < r1) {
        base[(size_t)r * 64 + lane] = a0[rr];
        msg[(size_t)r * 64 + lane] = __float2bfloat16(a1[rr]);
      }
    }
  }
}

// ---- gather: pair loads (2 rows/instr), FULL predicated chunks — no tails.
// Padded slots load a clamped (already-hot) address and cndmask to zero:
// identical transaction set to the tailed version, minus serial tail overhead.
template <bool LN>
__global__ __launch_bounds__(256) void k_agg(
    const float* __restrict__ base, const __hip_bfloat16* __restrict__ msg,
    const int* __restrict__ offs, const int* __restrict__ nbr,
    const float* __restrict__ gamma, const float* __restrict__ beta,
    float* __restrict__ out, int nrows) {
  const int lane = threadIdx.x & 63;
  const int half = lane >> 5;   // which neighbor of each pair
  const int c = lane & 31;      // column-pair index (cols 2c, 2c+1)
  const int wid = (blockIdx.x * 256 + threadIdx.x) >> 6;
  const int nw = (gridDim.x * 256) >> 6;
  float gm = 1.0f, bt = 0.0f;
  if (LN) { gm = gamma[lane]; bt = beta[lane]; }
  const unsigned* msg32 = reinterpret_cast<const unsigned*>(msg);  // row = 32 dwords
  for (int r = wid; r < nrows; r += nw) {
    const int n0 = offs[r], n1 = offs[r + 1];
    const float bval = base[(size_t)r * 64 + lane];  // in flight during gather
    float agx = 0.0f, agy = 0.0f;
    for (int jb = n0; jb < n1; jb += 32) {  // every chunk is a full 16-pair batch
      int idx[16];
#pragma unroll
      for (int u = 0; u < 16; ++u) {
        int jj = jb + 2 * u + half;
        idx[u] = nbr[min(jj, n1 - 1)];      // clamped: hot line, no new sector
      }
      unsigned mv[16];
#pragma unroll
      for (int u = 0; u < 16; ++u) mv[u] = msg32[(idx[u] << 5) + c];
#pragma unroll
      for (int u = 0; u < 16; ++u) {
        if (jb + 2 * u + half >= n1) mv[u] = 0u;  // cndmask padded slots
        agx += bflo(mv[u]);
        agy += bfhi(mv[u]);
      }
    }
    // combine halves, then redistribute pair-sums to per-column lanes
    agx += __shfl_xor(agx, 32, 64);
    agy += __shfl_xor(agy, 32, 64);
    float tx = __shfl(agx, lane >> 1, 64);
    float ty = __shfl(agy, lane >> 1, 64);
    float ag = (lane & 1) ? ty : tx;
    const float rdeg = 1.0f / fmaxf((float)(n1 - n0), 1.0f);
    float val = fmaf(ag, rdeg, bval);
    if (LN) {
      float s = val;
#pragma unroll
      for (int off = 32; off > 0; off >>= 1) s += __shfl_xor(s, off, 64);
      const float mu = s * (1.0f / 64.0f);
      const float dv = val - mu;
      float v2 = dv * dv;
#pragma unroll
      for (int off = 32; off > 0; off >>= 1) v2 += __shfl_xor(v2, off, 64);
      const float var = v2 * (1.0f / 64.0f);
      val = fmaxf(fmaf(dv * rsqrtf(var + 1e-5f), gm, bt), 0.0f);
    }
    out[(size_t)r * 64 + lane] = val;
  }
}

extern "C" void kernel_launch(void* const* d_in, const int* in_sizes, int n_in,
                              void* d_out, int out_size, void* d_ws, size_t ws_size,
                              hipStream_t stream) {
  const float* vert = (const float*)d_in[0];
  const int* edges = (const int*)d_in[1];
  const float* W0 = (const float*)d_in[2];
  const float* b0 = (const float*)d_in[3];
  const float* W1 = (const float*)d_in[4];
  const float* b1 = (const float*)d_in[5];
  const float* lng = (const float*)d_in[6];
  const float* lnb = (const float*)d_in[7];
  float* base = (float*)d_out;  // base lives in d_out every layer

  const size_t HB = (size_t)NN * D_ * sizeof(float);  // 25.6 MB
  float* hbuf = (float*)d_ws;                                  // persistent h
  int* nbr = (int*)((char*)d_ws + HB);                         // 12.8 MB persistent
  char* msgreg = (char*)d_ws + HB + (size_t)2 * NE * 4;        // 12.8 MB region
  __hip_bfloat16* msg = (__hip_bfloat16*)msgreg;
  unsigned* items = (unsigned*)msgreg;  // CSR build temp (dead before msg)
  int* offs = (int*)((char*)d_ws + HB + (size_t)2 * NE * 4 + HB / 2);  // persistent
  // CSR scan temporaries live in d_out (dead before gemm2-L0 writes base)
  int* cnts = (int*)d_out;        // SCN ints
  int* sscan = cnts + SCN;        // SCN ints
  int* bsum = sscan + SCN;        // SCB ints

  // ---- CSR build: bucket sort, zero global atomics
  k_s1count<<<NB1, 256, 0, stream>>>(edges, cnts);
  k_scanA<<<SCB, 1024, 0, stream>>>(cnts, sscan, bsum, SCN);
  k_scanB<<<1, 256, 0, stream>>>(bsum, SCB);
  k_scanC<<<(SCN + 255) / 256, 256, 0, stream>>>(sscan, bsum, SCN);
  k_s1scatter<<<NB1, 256, 0, stream>>>(edges, sscan, items);
  k_s2build<<<NBUCK, 256, 0, stream>>>(items, sscan, offs, nbr);

  const int GB = 2048;   // agg grid (8192 waves = device wave capacity)
  const int GG = 1024;   // gemm2 grid

  for (int l = 0; l < 3; ++l) {
    const float* hcur = (l == 0) ? vert : hbuf;
    k_gemm2<<<GG, 256, 0, stream>>>(hcur, W0 + l * 4096, b0 + l * 64,
                                    W1 + l * 4096, b1 + l * 64, base, msg, NN);
    if (l < 2) {
      k_agg<true><<<GB, 256, 0, stream>>>(base, msg, offs, nbr,
                                          lng + l * 64, lnb + l * 64, hbuf, NN);
    } else {
      k_agg<false><<<GB, 256, 0, stream>>>(base, msg, offs, nbr,
                                           nullptr, nullptr, base, NN);
    }
  }
}

// Round 15
// 398.038 us; speedup vs baseline: 1.2386x; 1.0563x over previous
//
#include <hip/hip_runtime.h>
#include <hip/hip_bf16.h>

constexpr int D_ = 64;
constexpr int NN = 100000;
constexpr int NE = 1600000;
constexpr int RB = 8;        // rows per wave-batch in gemm phase

// ---- sort-CSR parameters
constexpr int BUCK_SH = 7;                         // 128 nodes per bucket
constexpr int NBUCK = (NN + 127) >> BUCK_SH;       // 782
constexpr int NB1 = 256;                           // S1 grid
constexpr int NQ4 = NE / 4;                        // 400000 quads
constexpr int QPB = (NQ4 + NB1 - 1) / NB1;         // 1563 quads/block
constexpr int SCN = NBUCK * NB1;                   // 200192 count entries
constexpr int SCB = (SCN + 1023) / 1024;           // 196 scan blocks

__device__ __forceinline__ float bflo(unsigned v) { return __uint_as_float(v << 16); }
__device__ __forceinline__ float bfhi(unsigned v) { return __uint_as_float(v & 0xffff0000u); }

// ---- S1A: per-block LDS histogram of endpoint buckets (no global atomics)
__global__ __launch_bounds__(256) void k_s1count(const int* __restrict__ edges,
                                                 int* __restrict__ cnts) {
  __shared__ int hist[NBUCK];
  for (int i = threadIdx.x; i < NBUCK; i += 256) hist[i] = 0;
  __syncthreads();
  const int q0 = blockIdx.x * QPB;
  const int q1 = min(q0 + QPB, NQ4);
  for (int q = q0 + (int)threadIdx.x; q < q1; q += 256) {
    const int4* ep = reinterpret_cast<const int4*>(edges + 8 * q);
    int4 a = ep[0], b = ep[1];
    atomicAdd(&hist[a.x >> BUCK_SH], 1);
    atomicAdd(&hist[a.y >> BUCK_SH], 1);
    atomicAdd(&hist[a.z >> BUCK_SH], 1);
    atomicAdd(&hist[a.w >> BUCK_SH], 1);
    atomicAdd(&hist[b.x >> BUCK_SH], 1);
    atomicAdd(&hist[b.y >> BUCK_SH], 1);
    atomicAdd(&hist[b.z >> BUCK_SH], 1);
    atomicAdd(&hist[b.w >> BUCK_SH], 1);
  }
  __syncthreads();
  for (int i = threadIdx.x; i < NBUCK; i += 256)
    cnts[i * NB1 + blockIdx.x] = hist[i];  // bucket-major for linear scan
}

// ---- hierarchical scan A (1024-wide blocks)
__global__ __launch_bounds__(1024) void k_scanA(const int* __restrict__ cnt,
                                                int* __restrict__ oscan,
                                                int* __restrict__ bsum, int n) {
  __shared__ int sd[1024];
  const int tid = threadIdx.x;
  const int i = blockIdx.x * 1024 + tid;
  int v = (i < n) ? cnt[i] : 0;
  sd[tid] = v;
  __syncthreads();
  for (int off = 1; off < 1024; off <<= 1) {
    int t = (tid >= off) ? sd[tid - off] : 0;
    __syncthreads();
    sd[tid] += t;
    __syncthreads();
  }
  if (i < n) oscan[i] = sd[tid] - v;
  if (tid == 1023) bsum[blockIdx.x] = sd[1023];
}

// ---- scan B: single 256-thread block scans block totals (exclusive, in place)
__global__ __launch_bounds__(256) void k_scanB(int* __restrict__ bsum, int nb) {
  __shared__ int sd[256];
  const int tid = threadIdx.x;
  int v = (tid < nb) ? bsum[tid] : 0;
  sd[tid] = v;
  __syncthreads();
  for (int off = 1; off < 256; off <<= 1) {
    int t = (tid >= off) ? sd[tid - off] : 0;
    __syncthreads();
    sd[tid] += t;
    __syncthreads();
  }
  if (tid < nb) bsum[tid] = sd[tid] - v;
}

// ---- scan C: add block base
__global__ __launch_bounds__(256) void k_scanC(int* __restrict__ oscan,
                                               const int* __restrict__ bsum, int n) {
  int i = blockIdx.x * 256 + threadIdx.x;
  if (i < n) oscan[i] += bsum[i >> 10];
}

// ---- S1B: scatter items into bucket-sorted array via LDS cursors.
__global__ __launch_bounds__(256) void k_s1scatter(const int* __restrict__ edges,
                                                   const int* __restrict__ sscan,
                                                   unsigned* __restrict__ items) {
  __shared__ int cur[NBUCK];
  for (int i = threadIdx.x; i < NBUCK; i += 256)
    cur[i] = sscan[i * NB1 + blockIdx.x];
  __syncthreads();
  const int q0 = blockIdx.x * QPB;
  const int q1 = min(q0 + QPB, NQ4);
  for (int q = q0 + (int)threadIdx.x; q < q1; q += 256) {
    const int4* ep = reinterpret_cast<const int4*>(edges + 8 * q);
    int4 a = ep[0], b = ep[1];
    int p;
    p = atomicAdd(&cur[a.y >> BUCK_SH], 1); items[p] = ((unsigned)(a.y & 127) << 17) | (unsigned)a.x;
    p = atomicAdd(&cur[a.x >> BUCK_SH], 1); items[p] = ((unsigned)(a.x & 127) << 17) | (unsigned)a.y;
    p = atomicAdd(&cur[a.w >> BUCK_SH], 1); items[p] = ((unsigned)(a.w & 127) << 17) | (unsigned)a.z;
    p = atomicAdd(&cur[a.z >> BUCK_SH], 1); items[p] = ((unsigned)(a.z & 127) << 17) | (unsigned)a.w;
    p = atomicAdd(&cur[b.y >> BUCK_SH], 1); items[p] = ((unsigned)(b.y & 127) << 17) | (unsigned)b.x;
    p = atomicAdd(&cur[b.x >> BUCK_SH], 1); items[p] = ((unsigned)(b.x & 127) << 17) | (unsigned)b.y;
    p = atomicAdd(&cur[b.w >> BUCK_SH], 1); items[p] = ((unsigned)(b.w & 127) << 17) | (unsigned)b.z;
    p = atomicAdd(&cur[b.z >> BUCK_SH], 1); items[p] = ((unsigned)(b.z & 127) << 17) | (unsigned)b.w;
  }
}

// ---- S2: one block per bucket -> local histogram+scan -> offs + nbr placement
__global__ __launch_bounds__(256) void k_s2build(const unsigned* __restrict__ items,
                                                 const int* __restrict__ sscan,
                                                 int* __restrict__ offs,
                                                 int* __restrict__ nbr) {
  const int b = blockIdx.x;
  const int lo = b << BUCK_SH;
  __shared__ int hist[128], scn[128];
  __shared__ int sbase, send;
  if (threadIdx.x == 0) {
    sbase = sscan[b * NB1];
    send = (b + 1 < NBUCK) ? sscan[(b + 1) * NB1] : 2 * NE;
  }
  if (threadIdx.x < 128) hist[threadIdx.x] = 0;
  __syncthreads();
  const int i0 = sbase, i1 = send;
  for (int i = i0 + (int)threadIdx.x; i < i1; i += 256)
    atomicAdd(&hist[items[i] >> 17], 1);
  __syncthreads();
  if (threadIdx.x < 128) scn[threadIdx.x] = hist[threadIdx.x];
  __syncthreads();
  for (int off = 1; off < 128; off <<= 1) {
    int t = (threadIdx.x < 128 && (int)threadIdx.x >= off) ? scn[threadIdx.x - off] : 0;
    __syncthreads();
    if (threadIdx.x < 128) scn[threadIdx.x] += t;
    __syncthreads();
  }
  if (threadIdx.x < 128) {
    int node = lo + threadIdx.x;
    int ex = sbase + scn[threadIdx.x] - hist[threadIdx.x];
    if (node < NN) offs[node] = ex;
    hist[threadIdx.x] = ex;  // placement cursor
  }
  __syncthreads();
  for (int i = i0 + (int)threadIdx.x; i < i1; i += 256) {
    unsigned it = items[i];
    int pos = atomicAdd(&hist[it >> 17], 1);
    nbr[pos] = (int)(it & 0x1FFFFu);
  }
  if (b == 0 && threadIdx.x == 0) offs[NN] = 2 * NE;
}

// W staged transposed+padded: wT[j*68+k] = W[k*64+j]
__device__ __forceinline__ void stage_w(const float* __restrict__ W, float* wT) {
  for (int i = threadIdx.x; i < 4096; i += 256) {
    int k = i >> 6, j = i & 63;
    wT[j * 68 + k] = W[i];
  }
}

// ---- gather helper: pair loads, clean full chunks + ONE predicated chunk
__device__ __forceinline__ float gather_row(const unsigned* __restrict__ msg32,
                                            const int* __restrict__ nbr,
                                            int n0, int n1, int half, int c,
                                            int lane) {
  float agx = 0.0f, agy = 0.0f;
  int jb = n0;
  for (; jb + 32 <= n1; jb += 32) {  // clean chunks: no predication overhead
    int idx[16];
#pragma unroll
    for (int u = 0; u < 16; ++u) idx[u] = nbr[jb + 2 * u + half];
    unsigned mv[16];
#pragma unroll
    for (int u = 0; u < 16; ++u) mv[u] = msg32[(idx[u] << 5) + c];
#pragma unroll
    for (int u = 0; u < 16; ++u) { agx += bflo(mv[u]); agy += bfhi(mv[u]); }
  }
  if (jb < n1) {  // single predicated chunk (full-width, no serial tail)
    int idx[16];
#pragma unroll
    for (int u = 0; u < 16; ++u) idx[u] = nbr[min(jb + 2 * u + half, n1 - 1)];
    unsigned mv[16];
#pragma unroll
    for (int u = 0; u < 16; ++u) mv[u] = msg32[(idx[u] << 5) + c];
#pragma unroll
    for (int u = 0; u < 16; ++u) {
      if (jb + 2 * u + half >= n1) mv[u] = 0u;
      agx += bflo(mv[u]);
      agy += bfhi(mv[u]);
    }
  }
  agx += __shfl_xor(agx, 32, 64);
  agy += __shfl_xor(agy, 32, 64);
  float tx = __shfl(agx, lane >> 1, 64);
  float ty = __shfl(agy, lane >> 1, 64);
  return (lane & 1) ? ty : tx;
}

// ---- gemm2: base = h@W0+b0 (f32), msg = bf16(h@W1+b1). (layer 0 only)
// k4 loop rolled (#pragma unroll 1): prevents LICM VGPR blowup (R8/R9).
__global__ __launch_bounds__(256) void k_gemm2(
    const float* __restrict__ h, const float* __restrict__ W0,
    const float* __restrict__ b0, const float* __restrict__ W1,
    const float* __restrict__ b1, float* __restrict__ base,
    __hip_bfloat16* __restrict__ msg, int nrows) {
  __shared__ float w0T[64 * 68];
  __shared__ float w1T[64 * 68];
  __shared__ float rbuf[4][RB * 64];
  stage_w(W0, w0T);
  stage_w(W1, w1T);
  __syncthreads();
  const int lane = threadIdx.x & 63;
  const int wv = threadIdx.x >> 6;
  const int wid = (blockIdx.x * 256 + threadIdx.x) >> 6;
  const int nw = (gridDim.x * 256) >> 6;
  const float bv0 = b0[lane], bv1 = b1[lane];
  const float4* wl0 = reinterpret_cast<const float4*>(&w0T[lane * 68]);
  const float4* wl1 = reinterpret_cast<const float4*>(&w1T[lane * 68]);
  float* myrows = rbuf[wv];

  const int chunk = (nrows + nw - 1) / nw;
  const int r0 = wid * chunk;
  const int r1 = min(r0 + chunk, nrows);
  if (r0 >= nrows) return;

  float st[RB];
#pragma unroll
  for (int rr = 0; rr < RB; ++rr) {
    int r = min(r0 + rr, nrows - 1);
    st[rr] = h[(size_t)r * 64 + lane];
  }
  for (int rb = r0; rb < r1; rb += RB) {
#pragma unroll
    for (int rr = 0; rr < RB; ++rr) myrows[rr * 64 + lane] = st[rr];
    const int nb = rb + RB;
    if (nb < r1) {
#pragma unroll
      for (int rr = 0; rr < RB; ++rr) {
        int r = min(nb + rr, nrows - 1);
        st[rr] = h[(size_t)r * 64 + lane];
      }
    }
    float a0[RB], a1[RB];
#pragma unroll
    for (int rr = 0; rr < RB; ++rr) { a0[rr] = bv0; a1[rr] = bv1; }
#pragma unroll 1
    for (int k4 = 0; k4 < 16; ++k4) {
      const float4 v0 = wl0[k4];
      const float4 v1 = wl1[k4];
#pragma unroll
      for (int rr = 0; rr < RB; ++rr) {
        float4 hv = *reinterpret_cast<const float4*>(&myrows[rr * 64 + k4 * 4]);
        a0[rr] = fmaf(hv.x, v0.x, a0[rr]); a1[rr] = fmaf(hv.x, v1.x, a1[rr]);
        a0[rr] = fmaf(hv.y, v0.y, a0[rr]); a1[rr] = fmaf(hv.y, v1.y, a1[rr]);
        a0[rr] = fmaf(hv.z, v0.z, a0[rr]); a1[rr] = fmaf(hv.z, v1.z, a1[rr]);
        a0[rr] = fmaf(hv.w, v0.w, a0[rr]); a1[rr] = fmaf(hv.w, v1.w, a1[rr]);
      }
    }
#pragma unroll
    for (int rr = 0; rr < RB; ++rr) {
      int r = rb + rr;
      if (r < r1) {
        base[(size_t)r * 64 + lane] = a0[rr];
        msg[(size_t)r * 64 + lane] = __float2bfloat16(a1[rr]);
      }
    }
  }
}

// ---- fused: agg(l) [+LN+ReLU] then gemm2(l+1), h row never touches global.
// base is updated in place (row-partitioned, read-before-write within wave).
__global__ __launch_bounds__(256) void k_fused(
    float* __restrict__ base, const __hip_bfloat16* __restrict__ msgin,
    __hip_bfloat16* __restrict__ msgout,
    const int* __restrict__ offs, const int* __restrict__ nbr,
    const float* __restrict__ gamma, const float* __restrict__ beta,
    const float* __restrict__ W0n, const float* __restrict__ b0n,
    const float* __restrict__ W1n, const float* __restrict__ b1n, int nrows) {
  __shared__ float w0T[64 * 68];
  __shared__ float w1T[64 * 68];
  __shared__ float rbuf[4][RB * 64];
  stage_w(W0n, w0T);
  stage_w(W1n, w1T);
  __syncthreads();
  const int lane = threadIdx.x & 63;
  const int wv = threadIdx.x >> 6;
  const int half = lane >> 5;
  const int c = lane & 31;
  const int wid = (blockIdx.x * 256 + threadIdx.x) >> 6;
  const int nw = (gridDim.x * 256) >> 6;
  const float gm = gamma[lane], bt = beta[lane];
  const float bv0 = b0n[lane], bv1 = b1n[lane];
  const float4* wl0 = reinterpret_cast<const float4*>(&w0T[lane * 68]);
  const float4* wl1 = reinterpret_cast<const float4*>(&w1T[lane * 68]);
  float* myrows = rbuf[wv];
  const unsigned* msg32 = reinterpret_cast<const unsigned*>(msgin);

  const int chunk = (nrows + nw - 1) / nw;
  const int r0 = wid * chunk;
  const int r1 = min(r0 + chunk, nrows);
  if (r0 >= nrows) return;

  for (int rb = r0; rb < r1; rb += RB) {
#pragma unroll 1
    for (int rr = 0; rr < RB; ++rr) {
      int r = rb + rr;
      if (r >= r1) break;  // wave-uniform
      const int n0 = offs[r], n1 = offs[r + 1];
      const float bval = base[(size_t)r * 64 + lane];
      float ag = gather_row(msg32, nbr, n0, n1, half, c, lane);
      const float rdeg = 1.0f / fmaxf((float)(n1 - n0), 1.0f);
      float val = fmaf(ag, rdeg, bval);
      // LayerNorm + ReLU
      float s = val;
#pragma unroll
      for (int off = 32; off > 0; off >>= 1) s += __shfl_xor(s, off, 64);
      const float mu = s * (1.0f / 64.0f);
      const float dv = val - mu;
      float v2 = dv * dv;
#pragma unroll
      for (int off = 32; off > 0; off >>= 1) v2 += __shfl_xor(v2, off, 64);
      const float var = v2 * (1.0f / 64.0f);
      val = fmaxf(fmaf(dv * rsqrtf(var + 1e-5f), gm, bt), 0.0f);
      myrows[rr * 64 + lane] = val;  // park h(l+1) row in LDS
    }
    // next-layer gemm on parked batch
    float a0[RB], a1[RB];
#pragma unroll
    for (int rr = 0; rr < RB; ++rr) { a0[rr] = bv0; a1[rr] = bv1; }
#pragma unroll 1
    for (int k4 = 0; k4 < 16; ++k4) {
      const float4 v0 = wl0[k4];
      const float4 v1 = wl1[k4];
#pragma unroll
      for (int rr = 0; rr < RB; ++rr) {
        float4 hv = *reinterpret_cast<const float4*>(&myrows[rr * 64 + k4 * 4]);
        a0[rr] = fmaf(hv.x, v0.x, a0[rr]); a1[rr] = fmaf(hv.x, v1.x, a1[rr]);
        a0[rr] = fmaf(hv.y, v0.y, a0[rr]); a1[rr] = fmaf(hv.y, v1.y, a1[rr]);
        a0[rr] = fmaf(hv.z, v0.z, a0[rr]); a1[rr] = fmaf(hv.z, v1.z, a1[rr]);
        a0[rr] = fmaf(hv.w, v0.w, a0[rr]); a1[rr] = fmaf(hv.w, v1.w, a1[rr]);
      }
    }
#pragma unroll
    for (int rr = 0; rr < RB; ++rr) {
      int r = rb + rr;
      if (r < r1) {
        base[(size_t)r * 64 + lane] = a0[rr];
        msgout[(size_t)r * 64 + lane] = __float2bfloat16(a1[rr]);
      }
    }
  }
}

// ---- final aggregation (layer 2, no LN): base += gather(msg)/deg, in place
__global__ __launch_bounds__(256) void k_aggF(
    float* __restrict__ base, const __hip_bfloat16* __restrict__ msg,
    const int* __restrict__ offs, const int* __restrict__ nbr, int nrows) {
  const int lane = threadIdx.x & 63;
  const int half = lane >> 5;
  const int c = lane & 31;
  const int wid = (blockIdx.x * 256 + threadIdx.x) >> 6;
  const int nw = (gridDim.x * 256) >> 6;
  const unsigned* msg32 = reinterpret_cast<const unsigned*>(msg);
  for (int r = wid; r < nrows; r += nw) {
    const int n0 = offs[r], n1 = offs[r + 1];
    const float bval = base[(size_t)r * 64 + lane];
    float ag = gather_row(msg32, nbr, n0, n1, half, c, lane);
    const float rdeg = 1.0f / fmaxf((float)(n1 - n0), 1.0f);
    base[(size_t)r * 64 + lane] = fmaf(ag, rdeg, bval);
  }
}

extern "C" void kernel_launch(void* const* d_in, const int* in_sizes, int n_in,
                              void* d_out, int out_size, void* d_ws, size_t ws_size,
                              hipStream_t stream) {
  const float* vert = (const float*)d_in[0];
  const int* edges = (const int*)d_in[1];
  const float* W0 = (const float*)d_in[2];
  const float* b0 = (const float*)d_in[3];
  const float* W1 = (const float*)d_in[4];
  const float* b1 = (const float*)d_in[5];
  const float* lng = (const float*)d_in[6];
  const float* lnb = (const float*)d_in[7];
  float* base = (float*)d_out;  // base lives in d_out all layers (in-place updates)

  // ws layout (38.8 MB of >=51.6):
  //   nbr 12.8 | msgA 12.8 (=NN*64*2) | msgB 12.8 | offs 0.4
  // R14 BUG FIX: msg buffer is NN*64 bf16 = 12.8 MB, NOT 2*NE*2 = 6.4 MB.
  const size_t NBR_B = (size_t)2 * NE * 4;        // 12.8 MB
  const size_t MSG_B = (size_t)NN * 64 * 2;       // 12.8 MB
  int* nbr = (int*)d_ws;
  char* msgAreg = (char*)d_ws + NBR_B;
  char* msgBreg = msgAreg + MSG_B;
  __hip_bfloat16* msgA = (__hip_bfloat16*)msgAreg;
  __hip_bfloat16* msgB = (__hip_bfloat16*)msgBreg;
  unsigned* items = (unsigned*)msgAreg;  // CSR temp: 2*NE*4 = 12.8 MB, fits msgA
  int* offs = (int*)(msgBreg + MSG_B);   // persistent, NN+1 ints
  // CSR scan temporaries in d_out (dead before gemm2-L0 writes base)
  int* cnts = (int*)d_out;        // SCN ints
  int* sscan = cnts + SCN;        // SCN ints
  int* bsum = sscan + SCN;        // SCB ints

  // ---- CSR build: bucket sort, zero global atomics
  k_s1count<<<NB1, 256, 0, stream>>>(edges, cnts);
  k_scanA<<<SCB, 1024, 0, stream>>>(cnts, sscan, bsum, SCN);
  k_scanB<<<1, 256, 0, stream>>>(bsum, SCB);
  k_scanC<<<(SCN + 255) / 256, 256, 0, stream>>>(sscan, bsum, SCN);
  k_s1scatter<<<NB1, 256, 0, stream>>>(edges, sscan, items);
  k_s2build<<<NBUCK, 256, 0, stream>>>(items, sscan, offs, nbr);

  const int GG = 1024;   // gemm2 grid
  const int GF = 768;    // fused grid: 3 blocks/CU (43 KB LDS), all resident
  const int GA = 2048;   // final agg grid

  // layer 0 gemms: vert -> base(d_out), msgA
  k_gemm2<<<GG, 256, 0, stream>>>(vert, W0, b0, W1, b1, base, msgA, NN);
  // fused agg(0)+LN0+gemm(1): base,msgA -> base,msgB
  k_fused<<<GF, 256, 0, stream>>>(base, msgA, msgB, offs, nbr,
                                  lng, lnb, W0 + 4096, b0 + 64,
                                  W1 + 4096, b1 + 64, NN);
  // fused agg(1)+LN1+gemm(2): base,msgB -> base,msgA
  k_fused<<<GF, 256, 0, stream>>>(base, msgB, msgA, offs, nbr,
                                  lng + 64, lnb + 64, W0 + 8192, b0 + 128,
                                  W1 + 8192, b1 + 128, NN);
  // final agg(2), no LN: base += gather(msgA)/deg  (in place -> d_out)
  k_aggF<<<GA, 256, 0, stream>>>(base, msgA, offs, nbr, NN);
}

// Round 16
// 365.338 us; speedup vs baseline: 1.3495x; 1.0895x over previous
//
#include <hip/hip_runtime.h>
#include <hip/hip_bf16.h>

constexpr int D_ = 64;
constexpr int NN = 100000;
constexpr int NE = 1600000;
constexpr int RB = 8;        // rows per wave-batch in gemm phase

// ---- sort-CSR parameters
constexpr int BUCK_SH = 7;                         // 128 nodes per bucket
constexpr int NBUCK = (NN + 127) >> BUCK_SH;       // 782
constexpr int NB1 = 256;                           // S1 grid
constexpr int NQ4 = NE / 4;                        // 400000 quads
constexpr int QPB = (NQ4 + NB1 - 1) / NB1;         // 1563 quads/block
constexpr int SCN = NBUCK * NB1;                   // 200192 count entries
constexpr int SCB = (SCN + 1023) / 1024;           // 196 scan blocks

// ---- S1A: per-block LDS histogram of endpoint buckets (no global atomics)
__global__ __launch_bounds__(256) void k_s1count(const int* __restrict__ edges,
                                                 int* __restrict__ cnts) {
  __shared__ int hist[NBUCK];
  for (int i = threadIdx.x; i < NBUCK; i += 256) hist[i] = 0;
  __syncthreads();
  const int q0 = blockIdx.x * QPB;
  const int q1 = min(q0 + QPB, NQ4);
  for (int q = q0 + (int)threadIdx.x; q < q1; q += 256) {
    const int4* ep = reinterpret_cast<const int4*>(edges + 8 * q);
    int4 a = ep[0], b = ep[1];
    atomicAdd(&hist[a.x >> BUCK_SH], 1);
    atomicAdd(&hist[a.y >> BUCK_SH], 1);
    atomicAdd(&hist[a.z >> BUCK_SH], 1);
    atomicAdd(&hist[a.w >> BUCK_SH], 1);
    atomicAdd(&hist[b.x >> BUCK_SH], 1);
    atomicAdd(&hist[b.y >> BUCK_SH], 1);
    atomicAdd(&hist[b.z >> BUCK_SH], 1);
    atomicAdd(&hist[b.w >> BUCK_SH], 1);
  }
  __syncthreads();
  for (int i = threadIdx.x; i < NBUCK; i += 256)
    cnts[i * NB1 + blockIdx.x] = hist[i];  // bucket-major for linear scan
}

// ---- hierarchical scan A (1024-wide blocks)
__global__ __launch_bounds__(1024) void k_scanA(const int* __restrict__ cnt,
                                                int* __restrict__ oscan,
                                                int* __restrict__ bsum, int n) {
  __shared__ int sd[1024];
  const int tid = threadIdx.x;
  const int i = blockIdx.x * 1024 + tid;
  int v = (i < n) ? cnt[i] : 0;
  sd[tid] = v;
  __syncthreads();
  for (int off = 1; off < 1024; off <<= 1) {
    int t = (tid >= off) ? sd[tid - off] : 0;
    __syncthreads();
    sd[tid] += t;
    __syncthreads();
  }
  if (i < n) oscan[i] = sd[tid] - v;
  if (tid == 1023) bsum[blockIdx.x] = sd[1023];
}

// ---- scan B: single 256-thread block scans block totals (exclusive, in place)
__global__ __launch_bounds__(256) void k_scanB(int* __restrict__ bsum, int nb) {
  __shared__ int sd[256];
  const int tid = threadIdx.x;
  int v = (tid < nb) ? bsum[tid] : 0;
  sd[tid] = v;
  __syncthreads();
  for (int off = 1; off < 256; off <<= 1) {
    int t = (tid >= off) ? sd[tid - off] : 0;
    __syncthreads();
    sd[tid] += t;
    __syncthreads();
  }
  if (tid < nb) bsum[tid] = sd[tid] - v;
}

// ---- scan C: add block base
__global__ __launch_bounds__(256) void k_scanC(int* __restrict__ oscan,
                                               const int* __restrict__ bsum, int n) {
  int i = blockIdx.x * 256 + threadIdx.x;
  if (i < n) oscan[i] += bsum[i >> 10];
}

// ---- S1B: scatter items into bucket-sorted array via LDS cursors.
__global__ __launch_bounds__(256) void k_s1scatter(const int* __restrict__ edges,
                                                   const int* __restrict__ sscan,
                                                   unsigned* __restrict__ items) {
  __shared__ int cur[NBUCK];
  for (int i = threadIdx.x; i < NBUCK; i += 256)
    cur[i] = sscan[i * NB1 + blockIdx.x];
  __syncthreads();
  const int q0 = blockIdx.x * QPB;
  const int q1 = min(q0 + QPB, NQ4);
  for (int q = q0 + (int)threadIdx.x; q < q1; q += 256) {
    const int4* ep = reinterpret_cast<const int4*>(edges + 8 * q);
    int4 a = ep[0], b = ep[1];
    int p;
    p = atomicAdd(&cur[a.y >> BUCK_SH], 1); items[p] = ((unsigned)(a.y & 127) << 17) | (unsigned)a.x;
    p = atomicAdd(&cur[a.x >> BUCK_SH], 1); items[p] = ((unsigned)(a.x & 127) << 17) | (unsigned)a.y;
    p = atomicAdd(&cur[a.w >> BUCK_SH], 1); items[p] = ((unsigned)(a.w & 127) << 17) | (unsigned)a.z;
    p = atomicAdd(&cur[a.z >> BUCK_SH], 1); items[p] = ((unsigned)(a.z & 127) << 17) | (unsigned)a.w;
    p = atomicAdd(&cur[b.y >> BUCK_SH], 1); items[p] = ((unsigned)(b.y & 127) << 17) | (unsigned)b.x;
    p = atomicAdd(&cur[b.x >> BUCK_SH], 1); items[p] = ((unsigned)(b.x & 127) << 17) | (unsigned)b.y;
    p = atomicAdd(&cur[b.w >> BUCK_SH], 1); items[p] = ((unsigned)(b.w & 127) << 17) | (unsigned)b.z;
    p = atomicAdd(&cur[b.z >> BUCK_SH], 1); items[p] = ((unsigned)(b.z & 127) << 17) | (unsigned)b.w;
  }
}

// ---- S2: one block per bucket -> local histogram+scan -> offs + nbr placement
__global__ __launch_bounds__(256) void k_s2build(const unsigned* __restrict__ items,
                                                 const int* __restrict__ sscan,
                                                 int* __restrict__ offs,
                                                 int* __restrict__ nbr) {
  const int b = blockIdx.x;
  const int lo = b << BUCK_SH;
  __shared__ int hist[128], scn[128];
  __shared__ int sbase, send;
  if (threadIdx.x == 0) {
    sbase = sscan[b * NB1];
    send = (b + 1 < NBUCK) ? sscan[(b + 1) * NB1] : 2 * NE;
  }
  if (threadIdx.x < 128) hist[threadIdx.x] = 0;
  __syncthreads();
  const int i0 = sbase, i1 = send;
  for (int i = i0 + (int)threadIdx.x; i < i1; i += 256)
    atomicAdd(&hist[items[i] >> 17], 1);
  __syncthreads();
  if (threadIdx.x < 128) scn[threadIdx.x] = hist[threadIdx.x];
  __syncthreads();
  for (int off = 1; off < 128; off <<= 1) {
    int t = (threadIdx.x < 128 && (int)threadIdx.x >= off) ? scn[threadIdx.x - off] : 0;
    __syncthreads();
    if (threadIdx.x < 128) scn[threadIdx.x] += t;
    __syncthreads();
  }
  if (threadIdx.x < 128) {
    int node = lo + threadIdx.x;
    int ex = sbase + scn[threadIdx.x] - hist[threadIdx.x];
    if (node < NN) offs[node] = ex;
    hist[threadIdx.x] = ex;  // placement cursor
  }
  __syncthreads();
  for (int i = i0 + (int)threadIdx.x; i < i1; i += 256) {
    unsigned it = items[i];
    int pos = atomicAdd(&hist[it >> 17], 1);
    nbr[pos] = (int)(it & 0x1FFFFu);
  }
  if (b == 0 && threadIdx.x == 0) offs[NN] = 2 * NE;
}

// W staged transposed+padded: wT[j*68+k] = W[k*64+j]
__device__ __forceinline__ void stage_w(const float* __restrict__ W, float* wT) {
  for (int i = threadIdx.x; i < 4096; i += 256) {
    int k = i >> 6, j = i & 63;
    wT[j * 68 + k] = W[i];
  }
}

// fp8 encode: byte0 of cvt_pk_fp8_f32 (HW OCP e4m3 on gfx950)
__device__ __forceinline__ unsigned char f32_to_f8(float v) {
  return (unsigned char)(__builtin_amdgcn_cvt_pk_fp8_f32(v, v, 0, false) & 0xff);
}

// ---- quad-fp8 gather: row = 16 dwords (64 fp8 cols). lane = q*16+c:
// q = neighbor slot (4 rows per load instr), c = dword (cols 4c..4c+3).
// 32-neighbor chunks: 8 loads, 8x(2 cvt + 4 add) VALU.
__device__ __forceinline__ float gather_row_q8(const unsigned* __restrict__ msgu,
                                               const int* __restrict__ nbr,
                                               int n0, int n1, int q, int c,
                                               int lane) {
  float acc[4] = {0.0f, 0.0f, 0.0f, 0.0f};
  int jb = n0;
  for (; jb + 32 <= n1; jb += 32) {  // clean chunks
    int idx[8];
#pragma unroll
    for (int u = 0; u < 8; ++u) idx[u] = nbr[jb + 4 * u + q];
    unsigned mv[8];
#pragma unroll
    for (int u = 0; u < 8; ++u) mv[u] = msgu[(idx[u] << 4) + c];
#pragma unroll
    for (int u = 0; u < 8; ++u) {
      auto lo = __builtin_amdgcn_cvt_pk_f32_fp8(mv[u], false);
      auto hi = __builtin_amdgcn_cvt_pk_f32_fp8(mv[u], true);
      acc[0] += lo[0]; acc[1] += lo[1]; acc[2] += hi[0]; acc[3] += hi[1];
    }
  }
  if (jb < n1) {  // one predicated chunk (clamped idx -> hot line; zeroed pad)
    int idx[8];
#pragma unroll
    for (int u = 0; u < 8; ++u) idx[u] = nbr[min(jb + 4 * u + q, n1 - 1)];
    unsigned mv[8];
#pragma unroll
    for (int u = 0; u < 8; ++u) mv[u] = msgu[(idx[u] << 4) + c];
#pragma unroll
    for (int u = 0; u < 8; ++u) {
      if (jb + 4 * u + q >= n1) mv[u] = 0u;  // fp8 0x00 == +0
      auto lo = __builtin_amdgcn_cvt_pk_f32_fp8(mv[u], false);
      auto hi = __builtin_amdgcn_cvt_pk_f32_fp8(mv[u], true);
      acc[0] += lo[0]; acc[1] += lo[1]; acc[2] += hi[0]; acc[3] += hi[1];
    }
  }
  // reduce over q (xor 16/32 preserves c)
#pragma unroll
  for (int k = 0; k < 4; ++k) {
    acc[k] += __shfl_xor(acc[k], 16, 64);
    acc[k] += __shfl_xor(acc[k], 32, 64);
  }
  // col j lives at source lane j>>2, slot j&3
  float t0 = __shfl(acc[0], lane >> 2, 64);
  float t1 = __shfl(acc[1], lane >> 2, 64);
  float t2 = __shfl(acc[2], lane >> 2, 64);
  float t3 = __shfl(acc[3], lane >> 2, 64);
  const int s = lane & 3;
  return (s == 0) ? t0 : ((s == 1) ? t1 : ((s == 2) ? t2 : t3));
}

// ---- gemm2: base = h@W0+b0 (f32), msg = fp8(h@W1+b1). (layer 0 only)
// k4 loop rolled (#pragma unroll 1): prevents LICM VGPR blowup (R8/R9).
__global__ __launch_bounds__(256) void k_gemm2(
    const float* __restrict__ h, const float* __restrict__ W0,
    const float* __restrict__ b0, const float* __restrict__ W1,
    const float* __restrict__ b1, float* __restrict__ base,
    unsigned char* __restrict__ msg, int nrows) {
  __shared__ float w0T[64 * 68];
  __shared__ float w1T[64 * 68];
  __shared__ float rbuf[4][RB * 64];
  stage_w(W0, w0T);
  stage_w(W1, w1T);
  __syncthreads();
  const int lane = threadIdx.x & 63;
  const int wv = threadIdx.x >> 6;
  const int wid = (blockIdx.x * 256 + threadIdx.x) >> 6;
  const int nw = (gridDim.x * 256) >> 6;
  const float bv0 = b0[lane], bv1 = b1[lane];
  const float4* wl0 = reinterpret_cast<const float4*>(&w0T[lane * 68]);
  const float4* wl1 = reinterpret_cast<const float4*>(&w1T[lane * 68]);
  float* myrows = rbuf[wv];

  const int chunk = (nrows + nw - 1) / nw;
  const int r0 = wid * chunk;
  const int r1 = min(r0 + chunk, nrows);
  if (r0 >= nrows) return;

  float st[RB];
#pragma unroll
  for (int rr = 0; rr < RB; ++rr) {
    int r = min(r0 + rr, nrows - 1);
    st[rr] = h[(size_t)r * 64 + lane];
  }
  for (int rb = r0; rb < r1; rb += RB) {
#pragma unroll
    for (int rr = 0; rr < RB; ++rr) myrows[rr * 64 + lane] = st[rr];
    const int nb = rb + RB;
    if (nb < r1) {
#pragma unroll
      for (int rr = 0; rr < RB; ++rr) {
        int r = min(nb + rr, nrows - 1);
        st[rr] = h[(size_t)r * 64 + lane];
      }
    }
    float a0[RB], a1[RB];
#pragma unroll
    for (int rr = 0; rr < RB; ++rr) { a0[rr] = bv0; a1[rr] = bv1; }
#pragma unroll 1
    for (int k4 = 0; k4 < 16; ++k4) {
      const float4 v0 = wl0[k4];
      const float4 v1 = wl1[k4];
#pragma unroll
      for (int rr = 0; rr < RB; ++rr) {
        float4 hv = *reinterpret_cast<const float4*>(&myrows[rr * 64 + k4 * 4]);
        a0[rr] = fmaf(hv.x, v0.x, a0[rr]); a1[rr] = fmaf(hv.x, v1.x, a1[rr]);
        a0[rr] = fmaf(hv.y, v0.y, a0[rr]); a1[rr] = fmaf(hv.y, v1.y, a1[rr]);
        a0[rr] = fmaf(hv.z, v0.z, a0[rr]); a1[rr] = fmaf(hv.z, v1.z, a1[rr]);
        a0[rr] = fmaf(hv.w, v0.w, a0[rr]); a1[rr] = fmaf(hv.w, v1.w, a1[rr]);
      }
    }
#pragma unroll
    for (int rr = 0; rr < RB; ++rr) {
      int r = rb + rr;
      if (r < r1) {
        base[(size_t)r * 64 + lane] = a0[rr];
        msg[(size_t)r * 64 + lane] = f32_to_f8(a1[rr]);
      }
    }
  }
}

// ---- fused: agg(l) [+LN+ReLU] then gemm2(l+1), h row never touches global.
__global__ __launch_bounds__(256) void k_fused(
    float* __restrict__ base, const unsigned char* __restrict__ msgin,
    unsigned char* __restrict__ msgout,
    const int* __restrict__ offs, const int* __restrict__ nbr,
    const float* __restrict__ gamma, const float* __restrict__ beta,
    const float* __restrict__ W0n, const float* __restrict__ b0n,
    const float* __restrict__ W1n, const float* __restrict__ b1n, int nrows) {
  __shared__ float w0T[64 * 68];
  __shared__ float w1T[64 * 68];
  __shared__ float rbuf[4][RB * 64];
  stage_w(W0n, w0T);
  stage_w(W1n, w1T);
  __syncthreads();
  const int lane = threadIdx.x & 63;
  const int wv = threadIdx.x >> 6;
  const int q = lane >> 4;
  const int c = lane & 15;
  const int wid = (blockIdx.x * 256 + threadIdx.x) >> 6;
  const int nw = (gridDim.x * 256) >> 6;
  const float gm = gamma[lane], bt = beta[lane];
  const float bv0 = b0n[lane], bv1 = b1n[lane];
  const float4* wl0 = reinterpret_cast<const float4*>(&w0T[lane * 68]);
  const float4* wl1 = reinterpret_cast<const float4*>(&w1T[lane * 68]);
  float* myrows = rbuf[wv];
  const unsigned* msgu = reinterpret_cast<const unsigned*>(msgin);

  const int chunk = (nrows + nw - 1) / nw;
  const int r0 = wid * chunk;
  const int r1 = min(r0 + chunk, nrows);
  if (r0 >= nrows) return;

  for (int rb = r0; rb < r1; rb += RB) {
#pragma unroll 1
    for (int rr = 0; rr < RB; ++rr) {
      int r = rb + rr;
      if (r >= r1) break;  // wave-uniform
      const int n0 = offs[r], n1 = offs[r + 1];
      const float bval = base[(size_t)r * 64 + lane];
      float ag = gather_row_q8(msgu, nbr, n0, n1, q, c, lane);
      const float rdeg = 1.0f / fmaxf((float)(n1 - n0), 1.0f);
      float val = fmaf(ag, rdeg, bval);
      // LayerNorm + ReLU
      float s = val;
#pragma unroll
      for (int off = 32; off > 0; off >>= 1) s += __shfl_xor(s, off, 64);
      const float mu = s * (1.0f / 64.0f);
      const float dv = val - mu;
      float v2 = dv * dv;
#pragma unroll
      for (int off = 32; off > 0; off >>= 1) v2 += __shfl_xor(v2, off, 64);
      const float var = v2 * (1.0f / 64.0f);
      val = fmaxf(fmaf(dv * rsqrtf(var + 1e-5f), gm, bt), 0.0f);
      myrows[rr * 64 + lane] = val;  // park h(l+1) row in LDS
    }
    // next-layer gemm on parked batch
    float a0[RB], a1[RB];
#pragma unroll
    for (int rr = 0; rr < RB; ++rr) { a0[rr] = bv0; a1[rr] = bv1; }
#pragma unroll 1
    for (int k4 = 0; k4 < 16; ++k4) {
      const float4 v0 = wl0[k4];
      const float4 v1 = wl1[k4];
#pragma unroll
      for (int rr = 0; rr < RB; ++rr) {
        float4 hv = *reinterpret_cast<const float4*>(&myrows[rr * 64 + k4 * 4]);
        a0[rr] = fmaf(hv.x, v0.x, a0[rr]); a1[rr] = fmaf(hv.x, v1.x, a1[rr]);
        a0[rr] = fmaf(hv.y, v0.y, a0[rr]); a1[rr] = fmaf(hv.y, v1.y, a1[rr]);
        a0[rr] = fmaf(hv.z, v0.z, a0[rr]); a1[rr] = fmaf(hv.z, v1.z, a1[rr]);
        a0[rr] = fmaf(hv.w, v0.w, a0[rr]); a1[rr] = fmaf(hv.w, v1.w, a1[rr]);
      }
    }
#pragma unroll
    for (int rr = 0; rr < RB; ++rr) {
      int r = rb + rr;
      if (r < r1) {
        base[(size_t)r * 64 + lane] = a0[rr];
        msgout[(size_t)r * 64 + lane] = f32_to_f8(a1[rr]);
      }
    }
  }
}

// ---- final aggregation (layer 2, no LN): base += gather(msg)/deg, in place
__global__ __launch_bounds__(256) void k_aggF(
    float* __restrict__ base, const unsigned char* __restrict__ msg,
    const int* __restrict__ offs, const int* __restrict__ nbr, int nrows) {
  const int lane = threadIdx.x & 63;
  const int q = lane >> 4;
  const int c = lane & 15;
  const int wid = (blockIdx.x * 256 + threadIdx.x) >> 6;
  const int nw = (gridDim.x * 256) >> 6;
  const unsigned* msgu = reinterpret_cast<const unsigned*>(msg);
  for (int r = wid; r < nrows; r += nw) {
    const int n0 = offs[r], n1 = offs[r + 1];
    const float bval = base[(size_t)r * 64 + lane];
    float ag = gather_row_q8(msgu, nbr, n0, n1, q, c, lane);
    const float rdeg = 1.0f / fmaxf((float)(n1 - n0), 1.0f);
    base[(size_t)r * 64 + lane] = fmaf(ag, rdeg, bval);
  }
}

extern "C" void kernel_launch(void* const* d_in, const int* in_sizes, int n_in,
                              void* d_out, int out_size, void* d_ws, size_t ws_size,
                              hipStream_t stream) {
  const float* vert = (const float*)d_in[0];
  const int* edges = (const int*)d_in[1];
  const float* W0 = (const float*)d_in[2];
  const float* b0 = (const float*)d_in[3];
  const float* W1 = (const float*)d_in[4];
  const float* b1 = (const float*)d_in[5];
  const float* lng = (const float*)d_in[6];
  const float* lnb = (const float*)d_in[7];
  float* base = (float*)d_out;  // base lives in d_out all layers (in-place updates)

  // ws layout (26 MB of >=51.6):
  //   nbr 12.8 | creg 12.8 (items during CSR build; then msgA 6.4 + msgB 6.4) | offs
  const size_t NBR_B = (size_t)2 * NE * 4;        // 12.8 MB
  const size_t MSG_B = (size_t)NN * 64;           // 6.4 MB (fp8)
  int* nbr = (int*)d_ws;
  char* creg = (char*)d_ws + NBR_B;
  unsigned* items = (unsigned*)creg;              // 2*NE u32 = 12.8 MB
  unsigned char* msgA = (unsigned char*)creg;     // 6.4 MB
  unsigned char* msgB = (unsigned char*)(creg + MSG_B);  // 6.4 MB
  int* offs = (int*)(creg + NBR_B);               // persistent, NN+1 ints
  // CSR scan temporaries in d_out (dead before gemm2-L0 writes base)
  int* cnts = (int*)d_out;        // SCN ints
  int* sscan = cnts + SCN;        // SCN ints
  int* bsum = sscan + SCN;        // SCB ints

  // ---- CSR build: bucket sort, zero global atomics
  k_s1count<<<NB1, 256, 0, stream>>>(edges, cnts);
  k_scanA<<<SCB, 1024, 0, stream>>>(cnts, sscan, bsum, SCN);
  k_scanB<<<1, 256, 0, stream>>>(bsum, SCB);
  k_scanC<<<(SCN + 255) / 256, 256, 0, stream>>>(sscan, bsum, SCN);
  k_s1scatter<<<NB1, 256, 0, stream>>>(edges, sscan, items);
  k_s2build<<<NBUCK, 256, 0, stream>>>(items, sscan, offs, nbr);

  const int GG = 1024;   // gemm2 grid
  const int GF = 768;    // fused grid: 3 blocks/CU (43 KB LDS)
  const int GA = 2048;   // final agg grid

  // layer 0 gemms: vert -> base(d_out), msgA
  k_gemm2<<<GG, 256, 0, stream>>>(vert, W0, b0, W1, b1, base, msgA, NN);
  // fused agg(0)+LN0+gemm(1): base,msgA -> base,msgB
  k_fused<<<GF, 256, 0, stream>>>(base, msgA, msgB, offs, nbr,
                                  lng, lnb, W0 + 4096, b0 + 64,
                                  W1 + 4096, b1 + 64, NN);
  // fused agg(1)+LN1+gemm(2): base,msgB -> base,msgA
  k_fused<<<GF, 256, 0, stream>>>(base, msgB, msgA, offs, nbr,
                                  lng + 64, lnb + 64, W0 + 8192, b0 + 128,
                                  W1 + 8192, b1 + 128, NN);
  // final agg(2), no LN: base += gather(msgA)/deg  (in place -> d_out)
  k_aggF<<<GA, 256, 0, stream>>>(base, msgA, offs, nbr, NN);
}